// Round 1
// 489.026 us; speedup vs baseline: 1.1040x; 1.1040x over previous
//
#include <hip/hip_runtime.h>
#include <hip/hip_fp16.h>

#define B_ 128
#define T_ 128
#define I_ 1024
#define O_ 1024
#define M_ (B_*T_)          // 16384 rows of h
#define NOUT (M_*O_)        // 16777216 spike outputs, loss at index NOUT

typedef __attribute__((ext_vector_type(8))) _Float16 half8;  // 8 fp16 = 4 VGPR
typedef __attribute__((ext_vector_type(4))) float floatx4;   // MFMA acc

// async global->LDS, 16B per lane. LDS dest = wave-uniform base + lane*16.
__device__ __forceinline__ void gld_lds16(const void* g, void* l) {
    __builtin_amdgcn_global_load_lds((const __attribute__((address_space(1))) void*)g,
                                     (__attribute__((address_space(3))) void*)l,
                                     16, 0, 0);
}

// Workgroup barrier that waits ONLY on LDS ops (lgkmcnt(0)); does NOT drain
// vmcnt. 0xC07F = vmcnt 63 (bits 3:0 & 15:14), expcnt 7, lgkmcnt 0.
// Safe here: the inter-step protocol is LDS-only (lst/cnt); global loads are
// guarded by compiler vmcnt-before-use, global stores need no in-kernel wait.
__device__ __forceinline__ void barrier_lds_only() {
    asm volatile("" ::: "memory");
    __builtin_amdgcn_s_waitcnt(0xC07F);
    __builtin_amdgcn_s_barrier();
    asm volatile("" ::: "memory");
}

// Exact 3-way FP16 split: x = h + m + l + r with |r| <~ max(2^-33|x|, 2^-26).
// fp16 (11-bit significand) vs bf16 (8-bit): 3 planes cover ~33 bits, so the
// 6 largest cross-products (hh, hm, mh, mm, hl, lh) carry everything down to
// 2^-22 relative; dropped terms (ml, lm, ll) are <= 2^-33 — strictly MORE
// accurate than the previous 8-product bf16 scheme (dropped ll at 2^-32),
// with 25% fewer MFMAs. Each subtraction is exact (Sterbenz: cvt result is
// within 1 ulp of its input). fp16 denormal range handles |r1| < 2^-14 with
// absolute floor ~2^-26 — negligible for this problem's threshold margins.
__device__ __forceinline__ void split3h(float x, unsigned short& h,
                                        unsigned short& m, unsigned short& l) {
    __half f0 = __float2half(x);
    float r1 = x - __half2float(f0);
    __half f1 = __float2half(r1);
    float r2 = r1 - __half2float(f1);
    __half f2 = __float2half(r2);
    h = __half_as_ushort(f0);
    m = __half_as_ushort(f1);
    l = __half_as_ushort(f2);
}

// ---------------------------------------------------------------------------
// split_x: x [M,K] f32 -> 3 fp16 planes, same layout. Pure memory pass.
// ---------------------------------------------------------------------------
__global__ __launch_bounds__(256) void split_x(const float* __restrict__ X,
                                               unsigned short* __restrict__ Xh,
                                               unsigned short* __restrict__ Xm,
                                               unsigned short* __restrict__ Xl) {
    size_t base = ((size_t)blockIdx.x * 256 + threadIdx.x) * 4;
    float4 v = *(const float4*)(X + base);
    ushort4 hh, mm, ll;
    split3h(v.x, hh.x, mm.x, ll.x);
    split3h(v.y, hh.y, mm.y, ll.y);
    split3h(v.z, hh.z, mm.z, ll.z);
    split3h(v.w, hh.w, mm.w, ll.w);
    *(ushort4*)(Xh + base) = hh;
    *(ushort4*)(Xm + base) = mm;
    *(ushort4*)(Xl + base) = ll;
}

// ---------------------------------------------------------------------------
// split_wt: w [K][N] f32 -> three TRANSPOSED fp16 planes wt_p[N][K].
// ---------------------------------------------------------------------------
__global__ __launch_bounds__(256) void split_wt(const float* __restrict__ W,
                                                unsigned short* __restrict__ WTh,
                                                unsigned short* __restrict__ WTm,
                                                unsigned short* __restrict__ WTl) {
    __shared__ float t[64][65];
    const int tid = threadIdx.x;
    const int tx = tid & 63, ty4 = tid >> 6;
    const int r0 = blockIdx.x * 64, c0 = blockIdx.y * 64;
#pragma unroll
    for (int j = 0; j < 16; ++j) {
        int row = j * 4 + ty4;
        t[row][tx] = W[(size_t)(r0 + row) * O_ + c0 + tx];
    }
    __syncthreads();
#pragma unroll
    for (int j = 0; j < 16; ++j) {
        int i = j * 4 + ty4;
        float v = t[tx][i];
        unsigned short h, m, l;
        split3h(v, h, m, l);
        size_t off = (size_t)(c0 + i) * I_ + r0 + tx;
        WTh[off] = h; WTm[off] = m; WTl[off] = l;
    }
}

// ---------------------------------------------------------------------------
// h = x @ w, fp16 3-way-split MFMA, 6 of 9 plane products (hh,hm,mh,mm,hl,lh).
// 128x128 tile, BK=32, 256 threads, 4 waves x (64x64), mfma_f32_16x16x32_f16.
// 6 planes in LDS (48 KB) via global_load_lds with XOR chunk swizzle
// (bank conflicts 0). Structure identical to the verified bf16 version;
// only the dtype and product count changed.
// ---------------------------------------------------------------------------
__global__ __launch_bounds__(256, 3) void gemm_h_mfma(
        const unsigned short* __restrict__ Xh, const unsigned short* __restrict__ Xm,
        const unsigned short* __restrict__ Xl, const unsigned short* __restrict__ WTh,
        const unsigned short* __restrict__ WTm, const unsigned short* __restrict__ WTl,
        float* __restrict__ H) {
    const int K = I_, N = O_;
    __shared__ unsigned short P[6][128 * 32];   // 6 planes x 8 KB = 48 KB

    const int tid = threadIdx.x;
    const int lane = tid & 63;
    const int wid = tid >> 6;
    const int wrow = wid >> 1, wcol = wid & 1;
    const int l15 = lane & 15, quad = lane >> 4;
    const int bm = blockIdx.x * 128, bn = blockIdx.y * 128;

    const int srow = tid >> 2, sch = tid & 3;
    const int schg = sch ^ ((srow >> 1) & 3);
    const unsigned short* gsrc[6];
    gsrc[0] = Xh  + (size_t)(bm + srow) * K + schg * 8;
    gsrc[1] = Xm  + (size_t)(bm + srow) * K + schg * 8;
    gsrc[2] = Xl  + (size_t)(bm + srow) * K + schg * 8;
    gsrc[3] = WTh + (size_t)(bn + srow) * K + schg * 8;
    gsrc[4] = WTm + (size_t)(bn + srow) * K + schg * 8;
    gsrc[5] = WTl + (size_t)(bn + srow) * K + schg * 8;

    floatx4 acc[4][4];
#pragma unroll
    for (int mt = 0; mt < 4; ++mt)
#pragma unroll
        for (int nt = 0; nt < 4; ++nt) acc[mt][nt] = (floatx4)(0.f);

    for (int kt = 0; kt < 32; ++kt) {
        const int k0 = kt * 32;
        __syncthreads();                       // all reads of P done
#pragma unroll
        for (int p = 0; p < 6; ++p) {
            unsigned short* dst = (unsigned short*)P + p * 4096 + tid * 8;
            gld_lds16(gsrc[p] + k0, dst);
            gld_lds16(gsrc[p] + (size_t)64 * K + k0, dst + 2048);
        }
        __syncthreads();                       // vmcnt drain -> LDS visible

        half8 Af[3][4];
#pragma unroll
        for (int pa = 0; pa < 3; ++pa)
#pragma unroll
            for (int mt = 0; mt < 4; ++mt) {
                int row = wrow * 64 + mt * 16 + l15;
                int chk = quad ^ ((row >> 1) & 3);
                Af[pa][mt] = *(const half8*)((const unsigned short*)P + pa * 4096 + row * 32 + chk * 8);
            }
        // products: Bh*(Ah,Am,Al), Bm*(Ah,Am), Bl*(Ah)  — magnitudes down to 2^-22
#pragma unroll
        for (int pb = 0; pb < 3; ++pb) {
            half8 Bf[4];
#pragma unroll
            for (int nt = 0; nt < 4; ++nt) {
                int col = wcol * 64 + nt * 16 + l15;
                int chk = quad ^ ((col >> 1) & 3);
                Bf[nt] = *(const half8*)((const unsigned short*)P + (3 + pb) * 4096 + col * 32 + chk * 8);
            }
#pragma unroll
            for (int nt = 0; nt < 4; ++nt)
#pragma unroll
                for (int mt = 0; mt < 4; ++mt) {
                    acc[mt][nt] = __builtin_amdgcn_mfma_f32_16x16x32_f16(Af[0][mt], Bf[nt], acc[mt][nt], 0, 0, 0);
                    if (pb < 2)
                        acc[mt][nt] = __builtin_amdgcn_mfma_f32_16x16x32_f16(Af[1][mt], Bf[nt], acc[mt][nt], 0, 0, 0);
                    if (pb == 0)
                        acc[mt][nt] = __builtin_amdgcn_mfma_f32_16x16x32_f16(Af[2][mt], Bf[nt], acc[mt][nt], 0, 0, 0);
                }
        }
    }

    // epilogue: C/D row = quad*4 + reg, col = lane&15
#pragma unroll
    for (int mt = 0; mt < 4; ++mt)
#pragma unroll
        for (int nt = 0; nt < 4; ++nt) {
            int grow = bm + wrow * 64 + mt * 16 + quad * 4;
            int gcol = bn + wcol * 64 + nt * 16 + l15;
            float* hp = H + (size_t)grow * N + gcol;
#pragma unroll
            for (int r = 0; r < 4; ++r) hp[(size_t)r * N] = acc[mt][nt][r];
        }
}

// ---------------------------------------------------------------------------
// d = w^T w   (fp32 exact-class — kept exact deliberately: d feeds 128
// accumulating reset steps in the scan, so its error budget is tighter than h's).
// ---------------------------------------------------------------------------
__global__ __launch_bounds__(256) void gemm_wtw(const float* __restrict__ W,
                                                float* __restrict__ D) {
    const int K = I_, N = O_;
    __shared__ float As[32][68];
    __shared__ float Bs[32][68];
    const int tid = threadIdx.x;
    const int tx = tid & 15, ty = tid >> 4;
    const int bj = blockIdx.x * 64, bo = blockIdx.y * 64;
    const int lr = tid >> 4;
    const int lc = (tid & 15) << 2;

    float acc[4][4];
#pragma unroll
    for (int m = 0; m < 4; m++)
#pragma unroll
        for (int n = 0; n < 4; n++) acc[m][n] = 0.f;

    for (int k0 = 0; k0 < K; k0 += 32) {
        float4 a0 = *(const float4*)(W + (size_t)(k0 + lr) * N + bj + lc);
        float4 a1 = *(const float4*)(W + (size_t)(k0 + lr + 16) * N + bj + lc);
        float4 b0 = *(const float4*)(W + (size_t)(k0 + lr) * N + bo + lc);
        float4 b1 = *(const float4*)(W + (size_t)(k0 + lr + 16) * N + bo + lc);
        __syncthreads();
        *(float4*)&As[lr][lc] = a0; *(float4*)&As[lr + 16][lc] = a1;
        *(float4*)&Bs[lr][lc] = b0; *(float4*)&Bs[lr + 16][lc] = b1;
        __syncthreads();
#pragma unroll
        for (int k = 0; k < 32; ++k) {
            float4 av = *(const float4*)&As[k][ty * 4];
            float4 bv = *(const float4*)&Bs[k][tx * 4];
            float am[4] = {av.x, av.y, av.z, av.w};
            float bb[4] = {bv.x, bv.y, bv.z, bv.w};
#pragma unroll
            for (int m = 0; m < 4; m++)
#pragma unroll
                for (int n = 0; n < 4; n++) acc[m][n] += am[m] * bb[n];
        }
    }
#pragma unroll
    for (int m = 0; m < 4; m++) {
        float4 v = make_float4(acc[m][0], acc[m][1], acc[m][2], acc[m][3]);
        *(float4*)(D + (size_t)(bj + ty * 4 + m) * N + bo + tx * 4) = v;
    }
}

// inv_norm[o] = 1/(d[o][o] + 1e-8); also zero the spike counter.
__global__ void colnorm_diag(const float* __restrict__ D, float* __restrict__ invn,
                             unsigned int* __restrict__ counter) {
    int o = blockIdx.x * 256 + threadIdx.x;
    if (o == 0) *counter = 0u;
    invn[o] = 1.0f / (D[(size_t)o * O_ + o] + 1e-8f);
}

// ---------------------------------------------------------------------------
// Sequential scan: one block per sample; thread owns 4 contiguous neurons.
// ONE LDS-only barrier per step. NEW this round: the 4 per-u ballot appends
// share a SINGLE lane-0 atomicAdd + shfl (in-register prefix over the 4
// masks) — removes 3 LDS-atomic+shfl latencies from the inter-step critical
// path. List order is scrambled vs before, but rst summation order was
// already arbitrary (fp32 sum of ~n d-rows; passed with absmax 0).
// Race-safety: a barrier every step means no wave enters step t+1 before all
// finish t; step-t appends go to lst[(t+1)&1] while step-t reads use
// lst[t&1] -> disjoint buffers between consecutive barriers.
// ---------------------------------------------------------------------------
__global__ __launch_bounds__(256) void scan_kernel(const float* __restrict__ h,
                                                   const float* __restrict__ d,
                                                   const float* __restrict__ invn,
                                                   const float* __restrict__ bias,
                                                   const float* __restrict__ beta,
                                                   float* __restrict__ out,
                                                   unsigned int* __restrict__ spike_count) {
    __shared__ int lst[2][O_];
    __shared__ int cnt[T_ + 1];
    __shared__ unsigned int red[256];

    const int tid = threadIdx.x;
    const int lane = tid & 63;
    const int b = blockIdx.x;
    const int o4 = tid * 4;
    const float betav = beta[0];
    const float omb = 1.0f - betav;

    const float4 invn4 = *(const float4*)(invn + o4);
    const float4 b4 = *(const float4*)(bias + o4);
    float4 mem4 = make_float4(0.f, 0.f, 0.f, 0.f);

    for (int i = tid; i <= T_; i += 256) cnt[i] = 0;
    unsigned int local_count = 0;
    const float* hb = h + (size_t)b * T_ * O_;
    float* ob = out + (size_t)b * T_ * O_;
    const unsigned long long below = (lane == 63) ? 0xFFFFFFFFFFFFFFFFull >> 1
                                                  : ((1ull << lane) - 1ull);

    float4 hcur = *(const float4*)(hb + o4);   // t = 0
    __syncthreads();

    for (int t = 0; t < T_; ++t) {
        const int p = t & 1, q = p ^ 1;
        const int n = cnt[t];

        float4 hnext = make_float4(0.f, 0.f, 0.f, 0.f);
        if (t + 1 < T_) hnext = *(const float4*)(hb + (size_t)(t + 1) * O_ + o4);

        float4 rst = make_float4(0.f, 0.f, 0.f, 0.f);
        int i = 0;
        for (; i + 16 <= n; i += 16) {
            float4 v[16];
#pragma unroll
            for (int u = 0; u < 16; ++u) {
                const int j = lst[p][i + u];
                v[u] = *(const float4*)(d + (size_t)j * O_ + o4);
            }
#pragma unroll
            for (int u = 0; u < 16; ++u) {
                rst.x += v[u].x; rst.y += v[u].y;
                rst.z += v[u].z; rst.w += v[u].w;
            }
        }
        for (; i + 4 <= n; i += 4) {
            float4 v[4];
#pragma unroll
            for (int u = 0; u < 4; ++u) {
                const int j = lst[p][i + u];
                v[u] = *(const float4*)(d + (size_t)j * O_ + o4);
            }
#pragma unroll
            for (int u = 0; u < 4; ++u) {
                rst.x += v[u].x; rst.y += v[u].y;
                rst.z += v[u].z; rst.w += v[u].w;
            }
        }
        for (; i < n; ++i) {
            const int j = lst[p][i];
            float4 v = *(const float4*)(d + (size_t)j * O_ + o4);
            rst.x += v.x; rst.y += v.y; rst.z += v.z; rst.w += v.w;
        }

        mem4.x = (mem4.x - rst.x) * betav + hcur.x * omb;
        mem4.y = (mem4.y - rst.y) * betav + hcur.y * omb;
        mem4.z = (mem4.z - rst.z) * betav + hcur.z * omb;
        mem4.w = (mem4.w - rst.w) * betav + hcur.w * omb;

        const int s[4] = {(mem4.x * invn4.x - b4.x) > 0.0f,
                          (mem4.y * invn4.y - b4.y) > 0.0f,
                          (mem4.z * invn4.z - b4.z) > 0.0f,
                          (mem4.w * invn4.w - b4.w) > 0.0f};

        float4 sv = make_float4(s[0] ? 1.f : 0.f, s[1] ? 1.f : 0.f,
                                s[2] ? 1.f : 0.f, s[3] ? 1.f : 0.f);
        *(float4*)(ob + (size_t)t * O_ + o4) = sv;
        local_count += (unsigned)(s[0] + s[1] + s[2] + s[3]);

        // ballot-aggregated appends into lst[q] / cnt[t+1]: ONE atomic per wave
        unsigned long long mk0 = __ballot(s[0]);
        unsigned long long mk1 = __ballot(s[1]);
        unsigned long long mk2 = __ballot(s[2]);
        unsigned long long mk3 = __ballot(s[3]);
        const int c0 = __popcll(mk0), c1 = __popcll(mk1), c2 = __popcll(mk2);
        const int tot = c0 + c1 + c2 + __popcll(mk3);
        int base = 0;
        if (lane == 0 && tot) base = atomicAdd(&cnt[t + 1], tot);
        base = __shfl(base, 0, 64);
        if (s[0]) lst[q][base + __popcll(mk0 & below)] = o4 + 0;
        base += c0;
        if (s[1]) lst[q][base + __popcll(mk1 & below)] = o4 + 1;
        base += c1;
        if (s[2]) lst[q][base + __popcll(mk2 & below)] = o4 + 2;
        base += c2;
        if (s[3]) lst[q][base + __popcll(mk3 & below)] = o4 + 3;

        barrier_lds_only();
        hcur = hnext;
    }

    red[tid] = local_count;
    __syncthreads();
    for (int st = 128; st > 0; st >>= 1) {
        if (tid < st) red[tid] += red[tid + st];
        __syncthreads();
    }
    if (tid == 0) atomicAdd(spike_count, red[0]);
}

__global__ void finalize_loss(const unsigned int* __restrict__ spike_count,
                              float* __restrict__ loss_out) {
    *loss_out = 0.5f * ((float)(*spike_count) / 16777216.0f);
}

// ---------------------------------------------------------------------------
extern "C" void kernel_launch(void* const* d_in, const int* in_sizes, int n_in,
                              void* d_out, int out_size, void* d_ws, size_t ws_size,
                              hipStream_t stream) {
    const float* x    = (const float*)d_in[0];   // [B,T,I]
    const float* w    = (const float*)d_in[1];   // [I,O]
    const float* beta = (const float*)d_in[2];   // [1]
    const float* bias = (const float*)d_in[3];   // [O]
    float* out = (float*)d_out;                  // NOUT spikes + 1 loss

    // workspace layout (~170 MB)
    char* ws = (char*)d_ws;
    float* h    = (float*)ws;                                         // 64 MiB
    float* dmat = (float*)(ws + (size_t)67108864);                    // 4 MiB
    float* invn = (float*)(ws + (size_t)71303168);                    // 4 KiB
    unsigned int* cntp = (unsigned int*)(ws + (size_t)71307264);      // 4 KiB
    unsigned short* wt_h = (unsigned short*)(ws + (size_t)71311360);  // 2 MiB
    unsigned short* wt_m = (unsigned short*)(ws + (size_t)73408512);  // 2 MiB
    unsigned short* wt_l = (unsigned short*)(ws + (size_t)75505664);  // 2 MiB
    unsigned short* x_h  = (unsigned short*)(ws + (size_t)77602816);  // 32 MiB
    unsigned short* x_m  = (unsigned short*)(ws + (size_t)111157248); // 32 MiB
    unsigned short* x_l  = (unsigned short*)(ws + (size_t)144711680); // 32 MiB

    split_x<<<M_ * I_ / 1024, 256, 0, stream>>>(x, x_h, x_m, x_l);
    split_wt<<<dim3(I_ / 64, O_ / 64), 256, 0, stream>>>(w, wt_h, wt_m, wt_l);
    gemm_h_mfma<<<dim3(M_ / 128, O_ / 128), 256, 0, stream>>>(x_h, x_m, x_l,
                                                              wt_h, wt_m, wt_l, h);
    gemm_wtw<<<dim3(O_ / 64, O_ / 64), 256, 0, stream>>>(w, dmat);
    colnorm_diag<<<O_ / 256, 256, 0, stream>>>(dmat, invn, cntp);
    scan_kernel<<<B_, 256, 0, stream>>>(h, dmat, invn, bias, beta, out, cntp);
    finalize_loss<<<1, 1, 0, stream>>>(cntp, out + (size_t)NOUT);
}

// Round 2
// 456.261 us; speedup vs baseline: 1.1833x; 1.0718x over previous
//
#include <hip/hip_runtime.h>
#include <hip/hip_fp16.h>

#define B_ 128
#define T_ 128
#define I_ 1024
#define O_ 1024
#define M_ (B_*T_)          // 16384 rows of h
#define NOUT (M_*O_)        // 16777216 spike outputs, loss at index NOUT

typedef __attribute__((ext_vector_type(8))) _Float16 half8;  // 8 fp16 = 4 VGPR
typedef __attribute__((ext_vector_type(4))) float floatx4;   // MFMA acc

// async global->LDS, 16B per lane. LDS dest = wave-uniform base + lane*16.
__device__ __forceinline__ void gld_lds16(const void* g, void* l) {
    __builtin_amdgcn_global_load_lds((const __attribute__((address_space(1))) void*)g,
                                     (__attribute__((address_space(3))) void*)l,
                                     16, 0, 0);
}

// Workgroup barrier that waits ONLY on LDS ops (lgkmcnt(0)); does NOT drain
// vmcnt. 0xC07F = vmcnt 63 (bits 3:0 & 15:14), expcnt 7, lgkmcnt 0.
__device__ __forceinline__ void barrier_lds_only() {
    asm volatile("" ::: "memory");
    __builtin_amdgcn_s_waitcnt(0xC07F);
    __builtin_amdgcn_s_barrier();
    asm volatile("" ::: "memory");
}

// Exact 3-way FP16 split: x = h + m + l + r with |r| <~ max(2^-33|x|, 2^-26).
// 6 kept cross-products (hh, hm, mh, mm, hl, lh) carry everything down to
// 2^-22 relative; dropped terms (ml, lm, ll) are <= 2^-33.
__device__ __forceinline__ void split3h(float x, unsigned short& h,
                                        unsigned short& m, unsigned short& l) {
    __half f0 = __float2half(x);
    float r1 = x - __half2float(f0);
    __half f1 = __float2half(r1);
    float r2 = r1 - __half2float(f1);
    __half f2 = __float2half(r2);
    h = __half_as_ushort(f0);
    m = __half_as_ushort(f1);
    l = __half_as_ushort(f2);
}

// ---------------------------------------------------------------------------
// split_x: x [M,K] f32 -> 3 fp16 planes, same layout. Pure memory pass.
// ---------------------------------------------------------------------------
__global__ __launch_bounds__(256) void split_x(const float* __restrict__ X,
                                               unsigned short* __restrict__ Xh,
                                               unsigned short* __restrict__ Xm,
                                               unsigned short* __restrict__ Xl) {
    size_t base = ((size_t)blockIdx.x * 256 + threadIdx.x) * 4;
    float4 v = *(const float4*)(X + base);
    ushort4 hh, mm, ll;
    split3h(v.x, hh.x, mm.x, ll.x);
    split3h(v.y, hh.y, mm.y, ll.y);
    split3h(v.z, hh.z, mm.z, ll.z);
    split3h(v.w, hh.w, mm.w, ll.w);
    *(ushort4*)(Xh + base) = hh;
    *(ushort4*)(Xm + base) = mm;
    *(ushort4*)(Xl + base) = ll;
}

// ---------------------------------------------------------------------------
// split_wt: w [K][N] f32 -> three TRANSPOSED fp16 planes wt_p[N][K].
// ---------------------------------------------------------------------------
__global__ __launch_bounds__(256) void split_wt(const float* __restrict__ W,
                                                unsigned short* __restrict__ WTh,
                                                unsigned short* __restrict__ WTm,
                                                unsigned short* __restrict__ WTl) {
    __shared__ float t[64][65];
    const int tid = threadIdx.x;
    const int tx = tid & 63, ty4 = tid >> 6;
    const int r0 = blockIdx.x * 64, c0 = blockIdx.y * 64;
#pragma unroll
    for (int j = 0; j < 16; ++j) {
        int row = j * 4 + ty4;
        t[row][tx] = W[(size_t)(r0 + row) * O_ + c0 + tx];
    }
    __syncthreads();
#pragma unroll
    for (int j = 0; j < 16; ++j) {
        int i = j * 4 + ty4;
        float v = t[tx][i];
        unsigned short h, m, l;
        split3h(v, h, m, l);
        size_t off = (size_t)(c0 + i) * I_ + r0 + tx;
        WTh[off] = h; WTm[off] = m; WTl[off] = l;
    }
}

// ---------------------------------------------------------------------------
// h = x @ w, fp16 3-way-split MFMA, 6 of 9 plane products (hh,hm,mh,mm,hl,lh).
// NEW (r2): 128x256 tile, 512 threads, 8 waves x (64x64 output), DOUBLE-
// BUFFERED 6-plane LDS (2 x 72 KB = 144 KB, 1 block/CU). The stage for K-step
// kt+1 is issued at the TOP of kt's body, so the vmcnt(0) at kt+1's top waits
// on loads issued a full MFMA phase (~900 cyc) earlier -> near-zero residual,
// instead of the full L2/HBM latency the old single-buffer drain paid.
// One barrier + one vmcnt-only wait per K-step; lgkm waits left to the
// compiler. Same XOR chunk swizzle as r1 (0 bank conflicts). Accumulation
// order bit-identical to r1's gemm.
// Safety of read-before-overwrite: every ds_read is consumed by an MFMA in
// the same K-step (compiler inserts lgkmcnt before use), so all reads of
// buf[cur] complete before any wave reaches the next barrier and stages into
// the other buffer.
// ---------------------------------------------------------------------------
__global__ __launch_bounds__(512, 2) void gemm_h_mfma(
        const unsigned short* __restrict__ Xh, const unsigned short* __restrict__ Xm,
        const unsigned short* __restrict__ Xl, const unsigned short* __restrict__ WTh,
        const unsigned short* __restrict__ WTm, const unsigned short* __restrict__ WTl,
        float* __restrict__ H) {
    const int K = I_, N = O_;
    // per buffer: 3 A-planes x 4096 halves (8KB) + 3 B-planes x 8192 halves
    // (16KB) = 36864 halves = 72KB; x2 buffers = 144KB.
    __shared__ unsigned short P[2][36864];

    const int tid = threadIdx.x;
    const int lane = tid & 63;
    const int wid = tid >> 6;             // 0..7
    const int wrow = wid >> 2;            // 0..1 -> rows wrow*64
    const int wcol = wid & 3;             // 0..3 -> cols wcol*64
    const int l15 = lane & 15, quad = lane >> 4;
    const int bm = blockIdx.x * 128, bn = blockIdx.y * 256;

    // staging map: thread tid stages 16B chunks; srow 0..127, chunk swizzled
    const int srow = tid >> 2, sch = tid & 3;
    const int schg = sch ^ ((srow >> 1) & 3);
    const unsigned short* gsrcA[3];
    const unsigned short* gsrcB[3];
    gsrcA[0] = Xh  + (size_t)(bm + srow) * K + schg * 8;
    gsrcA[1] = Xm  + (size_t)(bm + srow) * K + schg * 8;
    gsrcA[2] = Xl  + (size_t)(bm + srow) * K + schg * 8;
    gsrcB[0] = WTh + (size_t)(bn + srow) * K + schg * 8;
    gsrcB[1] = WTm + (size_t)(bn + srow) * K + schg * 8;
    gsrcB[2] = WTl + (size_t)(bn + srow) * K + schg * 8;

    // stage K-tile kt into buffer kt&1: 9 gld_lds16 per thread (A:3, B:6)
    auto stage = [&](int kt) {
        unsigned short* wb = &P[0][0] + (size_t)(kt & 1) * 36864;
        const size_t k0 = (size_t)kt * 32;
#pragma unroll
        for (int p = 0; p < 3; ++p)
            gld_lds16(gsrcA[p] + k0, wb + p * 4096 + tid * 8);
#pragma unroll
        for (int p = 0; p < 3; ++p) {
            unsigned short* bb = wb + 12288 + p * 8192 + tid * 8;
            gld_lds16(gsrcB[p] + k0, bb);
            gld_lds16(gsrcB[p] + (size_t)128 * K + k0, bb + 4096);
        }
    };

    floatx4 acc[4][4];
#pragma unroll
    for (int mt = 0; mt < 4; ++mt)
#pragma unroll
        for (int nt = 0; nt < 4; ++nt) acc[mt][nt] = (floatx4)(0.f);

    stage(0);   // prologue

    for (int kt = 0; kt < 32; ++kt) {
        const unsigned short* rb = &P[0][0] + (size_t)(kt & 1) * 36864;

        // wait own kt-stage arrived (vmcnt(0); lgkm=31/exp=7 no-wait), then
        // barrier so everyone's stage is visible.
        asm volatile("" ::: "memory");
        __builtin_amdgcn_s_waitcnt(0x1F70);
        __builtin_amdgcn_s_barrier();
        asm volatile("" ::: "memory");

        // A fragments: 3 planes x 4 row-tiles
        half8 Af[3][4];
#pragma unroll
        for (int pa = 0; pa < 3; ++pa)
#pragma unroll
            for (int mt = 0; mt < 4; ++mt) {
                const int row = wrow * 64 + mt * 16 + l15;
                const int chk = quad ^ ((row >> 1) & 3);
                Af[pa][mt] = *(const half8*)(rb + pa * 4096 + row * 32 + chk * 8);
            }

        // issue next tile's stage EARLY -> in flight across this step's MFMAs
        if (kt < 31) stage(kt + 1);

#pragma unroll
        for (int pb = 0; pb < 3; ++pb) {
            half8 Bf[4];
#pragma unroll
            for (int nt = 0; nt < 4; ++nt) {
                const int col = wcol * 64 + nt * 16 + l15;
                const int chk = quad ^ ((col >> 1) & 3);
                Bf[nt] = *(const half8*)(rb + 12288 + pb * 8192 + col * 32 + chk * 8);
            }
#pragma unroll
            for (int nt = 0; nt < 4; ++nt)
#pragma unroll
                for (int mt = 0; mt < 4; ++mt) {
                    acc[mt][nt] = __builtin_amdgcn_mfma_f32_16x16x32_f16(Af[0][mt], Bf[nt], acc[mt][nt], 0, 0, 0);
                    if (pb < 2)
                        acc[mt][nt] = __builtin_amdgcn_mfma_f32_16x16x32_f16(Af[1][mt], Bf[nt], acc[mt][nt], 0, 0, 0);
                    if (pb == 0)
                        acc[mt][nt] = __builtin_amdgcn_mfma_f32_16x16x32_f16(Af[2][mt], Bf[nt], acc[mt][nt], 0, 0, 0);
                }
        }
    }

    // epilogue: C/D row = quad*4 + reg, col = lane&15
#pragma unroll
    for (int mt = 0; mt < 4; ++mt)
#pragma unroll
        for (int nt = 0; nt < 4; ++nt) {
            int grow = bm + wrow * 64 + mt * 16 + quad * 4;
            int gcol = bn + wcol * 64 + nt * 16 + l15;
            float* hp = H + (size_t)grow * N + gcol;
#pragma unroll
            for (int r = 0; r < 4; ++r) hp[(size_t)r * N] = acc[mt][nt][r];
        }
}

// ---------------------------------------------------------------------------
// d = w^T w   (fp32 exact-class — kept exact deliberately: d feeds 128
// accumulating reset steps in the scan, so its error budget is tighter than h's).
// ---------------------------------------------------------------------------
__global__ __launch_bounds__(256) void gemm_wtw(const float* __restrict__ W,
                                                float* __restrict__ D) {
    const int K = I_, N = O_;
    __shared__ float As[32][68];
    __shared__ float Bs[32][68];
    const int tid = threadIdx.x;
    const int tx = tid & 15, ty = tid >> 4;
    const int bj = blockIdx.x * 64, bo = blockIdx.y * 64;
    const int lr = tid >> 4;
    const int lc = (tid & 15) << 2;

    float acc[4][4];
#pragma unroll
    for (int m = 0; m < 4; m++)
#pragma unroll
        for (int n = 0; n < 4; n++) acc[m][n] = 0.f;

    for (int k0 = 0; k0 < K; k0 += 32) {
        float4 a0 = *(const float4*)(W + (size_t)(k0 + lr) * N + bj + lc);
        float4 a1 = *(const float4*)(W + (size_t)(k0 + lr + 16) * N + bj + lc);
        float4 b0 = *(const float4*)(W + (size_t)(k0 + lr) * N + bo + lc);
        float4 b1 = *(const float4*)(W + (size_t)(k0 + lr + 16) * N + bo + lc);
        __syncthreads();
        *(float4*)&As[lr][lc] = a0; *(float4*)&As[lr + 16][lc] = a1;
        *(float4*)&Bs[lr][lc] = b0; *(float4*)&Bs[lr + 16][lc] = b1;
        __syncthreads();
#pragma unroll
        for (int k = 0; k < 32; ++k) {
            float4 av = *(const float4*)&As[k][ty * 4];
            float4 bv = *(const float4*)&Bs[k][tx * 4];
            float am[4] = {av.x, av.y, av.z, av.w};
            float bb[4] = {bv.x, bv.y, bv.z, bv.w};
#pragma unroll
            for (int m = 0; m < 4; m++)
#pragma unroll
                for (int n = 0; n < 4; n++) acc[m][n] += am[m] * bb[n];
        }
    }
#pragma unroll
    for (int m = 0; m < 4; m++) {
        float4 v = make_float4(acc[m][0], acc[m][1], acc[m][2], acc[m][3]);
        *(float4*)(D + (size_t)(bj + ty * 4 + m) * N + bo + tx * 4) = v;
    }
}

// inv_norm[o] = 1/(d[o][o] + 1e-8); also zero the spike counter.
__global__ void colnorm_diag(const float* __restrict__ D, float* __restrict__ invn,
                             unsigned int* __restrict__ counter) {
    int o = blockIdx.x * 256 + threadIdx.x;
    if (o == 0) *counter = 0u;
    invn[o] = 1.0f / (D[(size_t)o * O_ + o] + 1e-8f);
}

// ---------------------------------------------------------------------------
// Sequential scan: one block per sample; thread owns 4 contiguous neurons.
// ONE LDS-only barrier per step; single lane-0 atomicAdd + shfl shared by the
// 4 per-u ballot appends (in-register prefix over the 4 masks).
// Race-safety: a barrier every step means no wave enters step t+1 before all
// finish t; step-t appends go to lst[(t+1)&1] while step-t reads use
// lst[t&1] -> disjoint buffers between consecutive barriers.
// ---------------------------------------------------------------------------
__global__ __launch_bounds__(256) void scan_kernel(const float* __restrict__ h,
                                                   const float* __restrict__ d,
                                                   const float* __restrict__ invn,
                                                   const float* __restrict__ bias,
                                                   const float* __restrict__ beta,
                                                   float* __restrict__ out,
                                                   unsigned int* __restrict__ spike_count) {
    __shared__ int lst[2][O_];
    __shared__ int cnt[T_ + 1];
    __shared__ unsigned int red[256];

    const int tid = threadIdx.x;
    const int lane = tid & 63;
    const int b = blockIdx.x;
    const int o4 = tid * 4;
    const float betav = beta[0];
    const float omb = 1.0f - betav;

    const float4 invn4 = *(const float4*)(invn + o4);
    const float4 b4 = *(const float4*)(bias + o4);
    float4 mem4 = make_float4(0.f, 0.f, 0.f, 0.f);

    for (int i = tid; i <= T_; i += 256) cnt[i] = 0;
    unsigned int local_count = 0;
    const float* hb = h + (size_t)b * T_ * O_;
    float* ob = out + (size_t)b * T_ * O_;
    const unsigned long long below = (lane == 63) ? 0xFFFFFFFFFFFFFFFFull >> 1
                                                  : ((1ull << lane) - 1ull);

    float4 hcur = *(const float4*)(hb + o4);   // t = 0
    __syncthreads();

    for (int t = 0; t < T_; ++t) {
        const int p = t & 1, q = p ^ 1;
        const int n = cnt[t];

        float4 hnext = make_float4(0.f, 0.f, 0.f, 0.f);
        if (t + 1 < T_) hnext = *(const float4*)(hb + (size_t)(t + 1) * O_ + o4);

        float4 rst = make_float4(0.f, 0.f, 0.f, 0.f);
        int i = 0;
        for (; i + 16 <= n; i += 16) {
            float4 v[16];
#pragma unroll
            for (int u = 0; u < 16; ++u) {
                const int j = lst[p][i + u];
                v[u] = *(const float4*)(d + (size_t)j * O_ + o4);
            }
#pragma unroll
            for (int u = 0; u < 16; ++u) {
                rst.x += v[u].x; rst.y += v[u].y;
                rst.z += v[u].z; rst.w += v[u].w;
            }
        }
        for (; i + 4 <= n; i += 4) {
            float4 v[4];
#pragma unroll
            for (int u = 0; u < 4; ++u) {
                const int j = lst[p][i + u];
                v[u] = *(const float4*)(d + (size_t)j * O_ + o4);
            }
#pragma unroll
            for (int u = 0; u < 4; ++u) {
                rst.x += v[u].x; rst.y += v[u].y;
                rst.z += v[u].z; rst.w += v[u].w;
            }
        }
        for (; i < n; ++i) {
            const int j = lst[p][i];
            float4 v = *(const float4*)(d + (size_t)j * O_ + o4);
            rst.x += v.x; rst.y += v.y; rst.z += v.z; rst.w += v.w;
        }

        mem4.x = (mem4.x - rst.x) * betav + hcur.x * omb;
        mem4.y = (mem4.y - rst.y) * betav + hcur.y * omb;
        mem4.z = (mem4.z - rst.z) * betav + hcur.z * omb;
        mem4.w = (mem4.w - rst.w) * betav + hcur.w * omb;

        const int s[4] = {(mem4.x * invn4.x - b4.x) > 0.0f,
                          (mem4.y * invn4.y - b4.y) > 0.0f,
                          (mem4.z * invn4.z - b4.z) > 0.0f,
                          (mem4.w * invn4.w - b4.w) > 0.0f};

        float4 sv = make_float4(s[0] ? 1.f : 0.f, s[1] ? 1.f : 0.f,
                                s[2] ? 1.f : 0.f, s[3] ? 1.f : 0.f);
        *(float4*)(ob + (size_t)t * O_ + o4) = sv;
        local_count += (unsigned)(s[0] + s[1] + s[2] + s[3]);

        // ballot-aggregated appends into lst[q] / cnt[t+1]: ONE atomic per wave
        unsigned long long mk0 = __ballot(s[0]);
        unsigned long long mk1 = __ballot(s[1]);
        unsigned long long mk2 = __ballot(s[2]);
        unsigned long long mk3 = __ballot(s[3]);
        const int c0 = __popcll(mk0), c1 = __popcll(mk1), c2 = __popcll(mk2);
        const int tot = c0 + c1 + c2 + __popcll(mk3);
        int base = 0;
        if (lane == 0 && tot) base = atomicAdd(&cnt[t + 1], tot);
        base = __shfl(base, 0, 64);
        if (s[0]) lst[q][base + __popcll(mk0 & below)] = o4 + 0;
        base += c0;
        if (s[1]) lst[q][base + __popcll(mk1 & below)] = o4 + 1;
        base += c1;
        if (s[2]) lst[q][base + __popcll(mk2 & below)] = o4 + 2;
        base += c2;
        if (s[3]) lst[q][base + __popcll(mk3 & below)] = o4 + 3;

        barrier_lds_only();
        hcur = hnext;
    }

    red[tid] = local_count;
    __syncthreads();
    for (int st = 128; st > 0; st >>= 1) {
        if (tid < st) red[tid] += red[tid + st];
        __syncthreads();
    }
    if (tid == 0) atomicAdd(spike_count, red[0]);
}

__global__ void finalize_loss(const unsigned int* __restrict__ spike_count,
                              float* __restrict__ loss_out) {
    *loss_out = 0.5f * ((float)(*spike_count) / 16777216.0f);
}

// ---------------------------------------------------------------------------
extern "C" void kernel_launch(void* const* d_in, const int* in_sizes, int n_in,
                              void* d_out, int out_size, void* d_ws, size_t ws_size,
                              hipStream_t stream) {
    const float* x    = (const float*)d_in[0];   // [B,T,I]
    const float* w    = (const float*)d_in[1];   // [I,O]
    const float* beta = (const float*)d_in[2];   // [1]
    const float* bias = (const float*)d_in[3];   // [O]
    float* out = (float*)d_out;                  // NOUT spikes + 1 loss

    // workspace layout (~170 MB)
    char* ws = (char*)d_ws;
    float* h    = (float*)ws;                                         // 64 MiB
    float* dmat = (float*)(ws + (size_t)67108864);                    // 4 MiB
    float* invn = (float*)(ws + (size_t)71303168);                    // 4 KiB
    unsigned int* cntp = (unsigned int*)(ws + (size_t)71307264);      // 4 KiB
    unsigned short* wt_h = (unsigned short*)(ws + (size_t)71311360);  // 2 MiB
    unsigned short* wt_m = (unsigned short*)(ws + (size_t)73408512);  // 2 MiB
    unsigned short* wt_l = (unsigned short*)(ws + (size_t)75505664);  // 2 MiB
    unsigned short* x_h  = (unsigned short*)(ws + (size_t)77602816);  // 32 MiB
    unsigned short* x_m  = (unsigned short*)(ws + (size_t)111157248); // 32 MiB
    unsigned short* x_l  = (unsigned short*)(ws + (size_t)144711680); // 32 MiB

    split_x<<<M_ * I_ / 1024, 256, 0, stream>>>(x, x_h, x_m, x_l);
    split_wt<<<dim3(I_ / 64, O_ / 64), 256, 0, stream>>>(w, wt_h, wt_m, wt_l);
    gemm_h_mfma<<<dim3(M_ / 128, O_ / 256), 512, 0, stream>>>(x_h, x_m, x_l,
                                                              wt_h, wt_m, wt_l, h);
    gemm_wtw<<<dim3(O_ / 64, O_ / 64), 256, 0, stream>>>(w, dmat);
    colnorm_diag<<<O_ / 256, 256, 0, stream>>>(dmat, invn, cntp);
    scan_kernel<<<B_, 256, 0, stream>>>(h, dmat, invn, bias, beta, out, cntp);
    finalize_loss<<<1, 1, 0, stream>>>(cntp, out + (size_t)NOUT);
}